// Round 3
// baseline (596.415 us; speedup 1.0000x reference)
//
#include <hip/hip_runtime.h>

// Per-point expert-indexed MLP: h = LeakyReLU(h @ W[idx] + b[idx]) x3.
// Counting-sort points by expert (segments padded to 1024) so each mlp block
// is expert-uniform; weights staged once per block in LDS (4.8 KB, broadcast
// reads). KEY CHANGE vs R2: M=4 points per thread so every ds_read_b128
// weight fragment feeds 16 FMAs (LDS-pipe demand /4: ~43us -> ~11us), and the
// scatter kernel stages sorted x rows (7 floats + point id) so mlp's global
// reads are coalesced streams, not random gathers.
//
// 3 dispatches: k_hist -> k_scatter (scan fused, stages x) -> k_mlp.

#define L_EXP 16
#define IN0   7
#define C0    16
#define C1    32
#define C2    16
#define NEG   0.2f
#define BLK   256
#define HBLK  64
#define MPT   4              // points per thread in k_mlp
#define SEGPAD (BLK * MPT)   // 1024: per-expert segment padding

// ws layout (int32):
//   [0..15]    counts per expert        (published by k_scatter block 0)
//   [16..32]   padded seg offsets, [32]=padded total (published by block 0)
//   [48..63]   scatter cursors          (zeroed by k_hist block 0)
//   [64..1087] partial histograms (HBLK x 16, from k_hist)
//   float idx 4096.. : staged rows, 8 floats/slot: x[0..6], as_float(point id)
#define WS_CUR   48
#define WS_PART  64
#define WS_STAGE 4096

__global__ void k_hist(const int* __restrict__ idx, int n, int* __restrict__ ws) {
    __shared__ int bins[L_EXP];
    int t = threadIdx.x;
    if (t < L_EXP) bins[t] = 0;
    __syncthreads();
    for (int i = blockIdx.x * blockDim.x + t; i < n; i += gridDim.x * blockDim.x)
        atomicAdd(&bins[idx[i] & 15], 1);
    __syncthreads();
    if (t < L_EXP) {
        ws[WS_PART + blockIdx.x * L_EXP + t] = bins[t];
        if (blockIdx.x == 0) ws[WS_CUR + t] = 0;  // zero cursors for k_scatter
    }
}

__global__ void k_scatter(const int* __restrict__ idx, const float* __restrict__ x,
                          int n, int* __restrict__ ws, float* __restrict__ stage) {
    __shared__ int scnt[L_EXP];    // total counts (recomputed per block, cheap)
    __shared__ int soff[L_EXP + 1];
    __shared__ int lcount[L_EXP];
    __shared__ int gbase[L_EXP];
    int t = threadIdx.x;
    if (t < L_EXP) {
        int s = 0;
        for (int b = 0; b < HBLK; ++b) s += ws[WS_PART + b * L_EXP + t];
        scnt[t] = s;
        lcount[t] = 0;
    }
    __syncthreads();
    if (t == 0) {
        int run = 0;
        for (int e = 0; e < L_EXP; ++e) {
            soff[e] = run;
            run += ((scnt[e] + SEGPAD - 1) / SEGPAD) * SEGPAD;
        }
        soff[L_EXP] = run;
        if (blockIdx.x == 0) {  // publish meta for k_mlp
            for (int e = 0; e < L_EXP; ++e) {
                ws[e] = scnt[e];
                ws[16 + e] = soff[e];
            }
            ws[32] = run;
        }
    }
    // per-point phase
    int i = blockIdx.x * BLK + t;
    bool act = (i < n);
    int e = 0, r = 0;
    float xv[IN0];
    if (act) {
        e = idx[i] & 15;
#pragma unroll
        for (int c = 0; c < IN0; ++c) xv[c] = x[i * IN0 + c];
        r = atomicAdd(&lcount[e], 1);
    }
    __syncthreads();
    if (t < L_EXP) gbase[t] = atomicAdd(&ws[WS_CUR + t], lcount[t]);
    __syncthreads();
    if (act) {
        int pos = soff[e] + gbase[e] + r;
        float4* sp = reinterpret_cast<float4*>(stage + (size_t)pos * 8);
        float4 a = make_float4(xv[0], xv[1], xv[2], xv[3]);
        float4 b = make_float4(xv[4], xv[5], xv[6], __int_as_float(i));
        sp[0] = a;
        sp[1] = b;
    }
}

__device__ __forceinline__ float leaky(float a) { return fmaxf(a, NEG * a); }

__global__ void __launch_bounds__(BLK, 2) k_mlp(
    const int* __restrict__ meta, const float* __restrict__ stage,
    const float* __restrict__ W0, const float* __restrict__ b0,
    const float* __restrict__ W1, const float* __restrict__ b1,
    const float* __restrict__ W2, const float* __restrict__ b2,
    float* __restrict__ out) {
    __shared__ __align__(16) float sW0[IN0 * C0];
    __shared__ __align__(16) float sB0[C0];
    __shared__ __align__(16) float sW1[C0 * C1];
    __shared__ __align__(16) float sB1[C1];
    __shared__ __align__(16) float sW2[C1 * C2];
    __shared__ __align__(16) float sB2[C2];

    int start = blockIdx.x * SEGPAD;
    if (start >= meta[32]) return;

    // whole block lies in one expert's padded segment
    int e = 0;
    while (start >= meta[16 + e + 1]) ++e;
    e = __builtin_amdgcn_readfirstlane(e);

    int t = threadIdx.x;
    {
        const float* w0p = W0 + e * (IN0 * C0);
        const float* w1p = W1 + e * (C0 * C1);
        const float* w2p = W2 + e * (C1 * C2);
        if (t < IN0 * C0) sW0[t] = w0p[t];
        if (t >= 128 && t < 128 + C0) sB0[t - 128] = b0[e * C0 + (t - 128)];
        if (t >= 160 && t < 160 + C1) sB1[t - 160] = b1[e * C1 + (t - 160)];
        if (t >= 192 && t < 192 + C2) sB2[t - 192] = b2[e * C2 + (t - 192)];
        for (int k = t; k < C0 * C1; k += BLK) sW1[k] = w1p[k];
        for (int k = t; k < C1 * C2; k += BLK) sW2[k] = w2p[k];
    }
    __syncthreads();

    int seg = meta[16 + e];
    int cnt = meta[e];
    int j0 = start - seg + t;

    // load M staged rows (coalesced 32B/lane); padded slots hold harmless poison
    float xv[MPT][IN0];
    int   pid[MPT];
    bool  act[MPT];
#pragma unroll
    for (int m = 0; m < MPT; ++m) {
        int j = j0 + m * BLK;
        act[m] = (j < cnt);
        const float4* sp = reinterpret_cast<const float4*>(stage + (size_t)(seg + j) * 8);
        float4 a = sp[0];
        float4 b = sp[1];
        xv[m][0] = a.x; xv[m][1] = a.y; xv[m][2] = a.z; xv[m][3] = a.w;
        xv[m][4] = b.x; xv[m][5] = b.y; xv[m][6] = b.z;
        pid[m] = __float_as_int(b.w);
    }

    // Layer 0: 7 -> 16
    float h0[MPT][C0];
#pragma unroll
    for (int og = 0; og < C0 / 4; ++og) {
        float4 bb = *reinterpret_cast<const float4*>(&sB0[og * 4]);
        float acc[MPT][4];
#pragma unroll
        for (int m = 0; m < MPT; ++m) {
            acc[m][0] = bb.x; acc[m][1] = bb.y; acc[m][2] = bb.z; acc[m][3] = bb.w;
        }
#pragma unroll
        for (int c = 0; c < IN0; ++c) {
            float4 w = *reinterpret_cast<const float4*>(&sW0[c * C0 + og * 4]);
#pragma unroll
            for (int m = 0; m < MPT; ++m) {
                acc[m][0] = fmaf(xv[m][c], w.x, acc[m][0]);
                acc[m][1] = fmaf(xv[m][c], w.y, acc[m][1]);
                acc[m][2] = fmaf(xv[m][c], w.z, acc[m][2]);
                acc[m][3] = fmaf(xv[m][c], w.w, acc[m][3]);
            }
        }
#pragma unroll
        for (int m = 0; m < MPT; ++m)
#pragma unroll
            for (int q = 0; q < 4; ++q) h0[m][og * 4 + q] = leaky(acc[m][q]);
    }

    // Layer 1: 16 -> 32
    float h1[MPT][C1];
#pragma unroll
    for (int og = 0; og < C1 / 4; ++og) {
        float4 bb = *reinterpret_cast<const float4*>(&sB1[og * 4]);
        float acc[MPT][4];
#pragma unroll
        for (int m = 0; m < MPT; ++m) {
            acc[m][0] = bb.x; acc[m][1] = bb.y; acc[m][2] = bb.z; acc[m][3] = bb.w;
        }
#pragma unroll
        for (int c = 0; c < C0; ++c) {
            float4 w = *reinterpret_cast<const float4*>(&sW1[c * C1 + og * 4]);
#pragma unroll
            for (int m = 0; m < MPT; ++m) {
                acc[m][0] = fmaf(h0[m][c], w.x, acc[m][0]);
                acc[m][1] = fmaf(h0[m][c], w.y, acc[m][1]);
                acc[m][2] = fmaf(h0[m][c], w.z, acc[m][2]);
                acc[m][3] = fmaf(h0[m][c], w.w, acc[m][3]);
            }
        }
#pragma unroll
        for (int m = 0; m < MPT; ++m)
#pragma unroll
            for (int q = 0; q < 4; ++q) h1[m][og * 4 + q] = leaky(acc[m][q]);
    }

    // Layer 2: 32 -> 16, store per float4
#pragma unroll
    for (int og = 0; og < C2 / 4; ++og) {
        float4 bb = *reinterpret_cast<const float4*>(&sB2[og * 4]);
        float acc[MPT][4];
#pragma unroll
        for (int m = 0; m < MPT; ++m) {
            acc[m][0] = bb.x; acc[m][1] = bb.y; acc[m][2] = bb.z; acc[m][3] = bb.w;
        }
#pragma unroll
        for (int c = 0; c < C1; ++c) {
            float4 w = *reinterpret_cast<const float4*>(&sW2[c * C2 + og * 4]);
#pragma unroll
            for (int m = 0; m < MPT; ++m) {
                acc[m][0] = fmaf(h1[m][c], w.x, acc[m][0]);
                acc[m][1] = fmaf(h1[m][c], w.y, acc[m][1]);
                acc[m][2] = fmaf(h1[m][c], w.z, acc[m][2]);
                acc[m][3] = fmaf(h1[m][c], w.w, acc[m][3]);
            }
        }
#pragma unroll
        for (int m = 0; m < MPT; ++m) {
            if (act[m]) {
                float4 o;
                o.x = leaky(acc[m][0]); o.y = leaky(acc[m][1]);
                o.z = leaky(acc[m][2]); o.w = leaky(acc[m][3]);
                reinterpret_cast<float4*>(out + (size_t)pid[m] * C2)[og] = o;
            }
        }
    }
}

extern "C" void kernel_launch(void* const* d_in, const int* in_sizes, int n_in,
                              void* d_out, int out_size, void* d_ws, size_t ws_size,
                              hipStream_t stream) {
    const float* x  = (const float*)d_in[0];
    const int*  idx = (const int*)d_in[1];
    const float* W0 = (const float*)d_in[2];
    const float* b0 = (const float*)d_in[3];
    const float* W1 = (const float*)d_in[4];
    const float* b1 = (const float*)d_in[5];
    const float* W2 = (const float*)d_in[6];
    const float* b2 = (const float*)d_in[7];
    float* out = (float*)d_out;

    int n = in_sizes[1];  // N
    int* ws = (int*)d_ws;
    float* stage = (float*)d_ws + WS_STAGE;

    k_hist<<<HBLK, BLK, 0, stream>>>(idx, n, ws);

    int nblk = (n + BLK - 1) / BLK;
    k_scatter<<<nblk, BLK, 0, stream>>>(idx, x, n, ws, stage);

    // padded total <= n + 16*(SEGPAD-1)
    int mblk = (n + L_EXP * (SEGPAD - 1) + SEGPAD - 1) / SEGPAD;
    k_mlp<<<mblk, BLK, 0, stream>>>(ws, stage, W0, b0, W1, b1, W2, b2, out);
}